// Round 8
// baseline (485.017 us; speedup 1.0000x reference)
//
#include <hip/hip_runtime.h>

#define BB 8
#define NN 1024
#define CC 768
#define HH 12
#define DD 64

typedef unsigned short u16;
typedef unsigned int u32;
typedef __attribute__((ext_vector_type(8))) short s16x8;
typedef __attribute__((ext_vector_type(4))) short s16x4;
typedef __attribute__((ext_vector_type(4))) float f32x4;
typedef __attribute__((ext_vector_type(2))) u32 u32x2;
typedef __attribute__((ext_vector_type(4))) u32 u32x4;

__device__ __forceinline__ float bf2f(u16 u) {
  u32 x = ((u32)u) << 16;
  return __builtin_bit_cast(float, x);
}
__device__ __forceinline__ u16 f2bf(float f) {
  u32 x = __builtin_bit_cast(u32, f);
  x += 0x7fffu + ((x >> 16) & 1u);
  return (u16)(x >> 16);
}
// hardware exp2 / log2 (v_exp_f32 / v_log_f32)
__device__ __forceinline__ float hw_exp2(float x) { return __builtin_amdgcn_exp2f(x); }
__device__ __forceinline__ float hw_log2(float x) { return __builtin_amdgcn_logf(x); }
// 16B LDS read as 2x8B (rows are 8B- but not 16B-aligned at conflict-free pitches)
__device__ __forceinline__ s16x8 lds_read8(const u16* p) {
  u32x2 a = *(const u32x2*)p;
  u32x2 b = *(const u32x2*)(p + 4);
  u32x4 m = {a.x, a.y, b.x, b.y};
  return __builtin_bit_cast(s16x8, m);
}
// pack f32 v into u32: low16 = bf16-trunc(v), high16 = bf16-trunc(v - hi).
// 4 VALU vs ~8 for RNE f2bf pair; err <= 2^-16|v|. Verified round-2/4.
__device__ __forceinline__ u32 packhl(float v) {
  u32 xv = __builtin_bit_cast(u32, v);
  float lo = v - __builtin_bit_cast(float, xv & 0xFFFF0000u);
  return (xv >> 16) | (__builtin_bit_cast(u32, lo) & 0xFFFF0000u);
}
// async global->LDS 16B/lane. LDS dest is wave-uniform base + lane*16.
__device__ __forceinline__ void gload_lds16(const u16* g, u16* l) {
  __builtin_amdgcn_global_load_lds(
      (const __attribute__((address_space(1))) u32*)g,
      (__attribute__((address_space(3))) u32*)l, 16, 0, 0);
}

// ---------------------------------------------------------------------------
// x fp32 -> bf16
// ---------------------------------------------------------------------------
__global__ __launch_bounds__(256) void convx_kernel(const float* __restrict__ in,
                                                    u16* __restrict__ out) {
  size_t i = ((size_t)blockIdx.x * 256 + threadIdx.x) * 8;
  f32x4 a = *(const f32x4*)(in + i);
  f32x4 b = *(const f32x4*)(in + i + 4);
  s16x8 r;
#pragma unroll
  for (int j = 0; j < 4; j++) { r[j] = (short)f2bf(a[j]); r[4 + j] = (short)f2bf(b[j]); }
  *(s16x8*)(out + i) = r;
}

// ---------------------------------------------------------------------------
// fp32 [R][C] -> bf16 [C][R]
// ---------------------------------------------------------------------------
__global__ __launch_bounds__(256) void transpose_kernel(const float* __restrict__ in,
                                                        u16* __restrict__ out,
                                                        int R, int C) {
  __shared__ float t[32][33];
  const int cl = threadIdx.x & 31, rq = threadIdx.x >> 5;
#pragma unroll
  for (int rr = 0; rr < 4; rr++) {
    int rl = rq * 4 + rr;
    t[rl][cl] = in[(size_t)(blockIdx.y * 32 + rl) * C + blockIdx.x * 32 + cl];
  }
  __syncthreads();
#pragma unroll
  for (int rr = 0; rr < 4; rr++) {
    int oc = rq * 4 + rr;
    out[(size_t)(blockIdx.x * 32 + oc) * R + blockIdx.y * 32 + cl] = f2bf(t[cl][oc]);
  }
}

// ---------------------------------------------------------------------------
// QKV GEMM: 128x128 tile, BK=32, dbuf prefetch w/ counted vmcnt (r7, neutral
// but kept) -> q,k [b][h][n][d] (q x0.125), v^T [b][h][d][n]
// ---------------------------------------------------------------------------
__global__ __launch_bounds__(256) void qkv_gemm(
    const u16* __restrict__ A, const u16* __restrict__ Bt, const float* __restrict__ bias,
    u16* __restrict__ qo, u16* __restrict__ ko, u16* __restrict__ vo) {
  __shared__ __align__(16) u16 As[2][128 * 32];
  __shared__ __align__(16) u16 Bs[2][128 * 32];
  const int tid = threadIdx.x;
  const int w = tid >> 6, lane = tid & 63, l15 = lane & 15, l4 = lane >> 4;
  const int wm = w & 1, wn = w >> 1;
  const int m0 = blockIdx.x * 128, n0 = blockIdx.y * 128;
  const int grow = lane >> 2, gcol = (lane & 3) * 8;  // staging row-in-chunk / u16 col

  const u16* ga0 = A + (size_t)(m0 + w * 32 + grow) * CC + gcol;
  const u16* gb0 = Bt + (size_t)(n0 + w * 32 + grow) * CC + gcol;

  f32x4 acc[4][4];
#pragma unroll
  for (int a = 0; a < 4; a++)
#pragma unroll
    for (int bb = 0; bb < 4; bb++) acc[a][bb] = (f32x4){0.f, 0.f, 0.f, 0.f};

  gload_lds16(ga0, &As[0][w * 1024]);
  gload_lds16(ga0 + (size_t)16 * CC, &As[0][w * 1024 + 512]);
  gload_lds16(gb0, &Bs[0][w * 1024]);
  gload_lds16(gb0 + (size_t)16 * CC, &Bs[0][w * 1024 + 512]);

  for (int t = 0; t < 24; ++t) {
    const int cb = t & 1, nb = cb ^ 1;
    if (t + 1 < 24) {
      const u16* ga = ga0 + (t + 1) * 32;
      const u16* gb = gb0 + (t + 1) * 32;
      gload_lds16(ga, &As[nb][w * 1024]);
      gload_lds16(ga + (size_t)16 * CC, &As[nb][w * 1024 + 512]);
      gload_lds16(gb, &Bs[nb][w * 1024]);
      gload_lds16(gb + (size_t)16 * CC, &Bs[nb][w * 1024 + 512]);
      asm volatile("s_waitcnt vmcnt(4)" ::: "memory");
    } else {
      asm volatile("s_waitcnt vmcnt(0)" ::: "memory");
    }
    __builtin_amdgcn_s_barrier();
    s16x8 af[4], bf[4];
#pragma unroll
    for (int a = 0; a < 4; a++) af[a] = *(const s16x8*)&As[cb][(wm * 64 + a * 16 + l15) * 32 + l4 * 8];
#pragma unroll
    for (int bb = 0; bb < 4; bb++) bf[bb] = *(const s16x8*)&Bs[cb][(wn * 64 + bb * 16 + l15) * 32 + l4 * 8];
#pragma unroll
    for (int a = 0; a < 4; a++)
#pragma unroll
      for (int bb = 0; bb < 4; bb++)
        acc[a][bb] = __builtin_amdgcn_mfma_f32_16x16x32_bf16(af[a], bf[bb], acc[a][bb], 0, 0, 0);
    asm volatile("s_waitcnt lgkmcnt(0)" ::: "memory");
    __builtin_amdgcn_s_barrier();
  }

  const int b = (m0 >> 10);
#pragma unroll
  for (int bb = 0; bb < 4; bb++) {
    int col = n0 + wn * 64 + bb * 16 + l15;
    int s = col / CC;
    int rem = col - s * CC;
    int h = rem >> 6, d = rem & 63;
    float bv = bias[col];
#pragma unroll
    for (int a = 0; a < 4; a++) {
      int row0 = m0 + wm * 64 + a * 16 + l4 * 4;
      int nt0 = row0 & (NN - 1);
      if (s == 2) {
        s16x4 pk;
#pragma unroll
        for (int r = 0; r < 4; r++) pk[r] = (short)f2bf(acc[a][bb][r] + bv);
        *(s16x4*)(vo + (((size_t)((b * HH + h) * DD + d)) << 10) + nt0) = pk;
      } else if (s == 0) {
#pragma unroll
        for (int r = 0; r < 4; r++)
          qo[(((size_t)((b * HH + h) * NN + nt0 + r)) << 6) + d] = f2bf((acc[a][bb][r] + bv) * 0.125f);
      } else {
#pragma unroll
        for (int r = 0; r < 4; r++)
          ko[(((size_t)((b * HH + h) * NN + nt0 + r)) << 6) + d] = f2bf(acc[a][bb][r] + bv);
      }
    }
  }
}

// ---------------------------------------------------------------------------
// Proj GEMM -> fp32 out (same structure)
// ---------------------------------------------------------------------------
__global__ __launch_bounds__(256) void proj_gemm(
    const u16* __restrict__ A, const u16* __restrict__ Bt, const float* __restrict__ bias,
    float* __restrict__ out) {
  __shared__ __align__(16) u16 As[2][128 * 32];
  __shared__ __align__(16) u16 Bs[2][128 * 32];
  const int tid = threadIdx.x;
  const int w = tid >> 6, lane = tid & 63, l15 = lane & 15, l4 = lane >> 4;
  const int wm = w & 1, wn = w >> 1;
  const int m0 = blockIdx.x * 128, n0 = blockIdx.y * 128;
  const int grow = lane >> 2, gcol = (lane & 3) * 8;

  const u16* ga0 = A + (size_t)(m0 + w * 32 + grow) * CC + gcol;
  const u16* gb0 = Bt + (size_t)(n0 + w * 32 + grow) * CC + gcol;

  f32x4 acc[4][4];
#pragma unroll
  for (int a = 0; a < 4; a++)
#pragma unroll
    for (int bb = 0; bb < 4; bb++) acc[a][bb] = (f32x4){0.f, 0.f, 0.f, 0.f};

  gload_lds16(ga0, &As[0][w * 1024]);
  gload_lds16(ga0 + (size_t)16 * CC, &As[0][w * 1024 + 512]);
  gload_lds16(gb0, &Bs[0][w * 1024]);
  gload_lds16(gb0 + (size_t)16 * CC, &Bs[0][w * 1024 + 512]);

  for (int t = 0; t < 24; ++t) {
    const int cb = t & 1, nb = cb ^ 1;
    if (t + 1 < 24) {
      const u16* ga = ga0 + (t + 1) * 32;
      const u16* gb = gb0 + (t + 1) * 32;
      gload_lds16(ga, &As[nb][w * 1024]);
      gload_lds16(ga + (size_t)16 * CC, &As[nb][w * 1024 + 512]);
      gload_lds16(gb, &Bs[nb][w * 1024]);
      gload_lds16(gb + (size_t)16 * CC, &Bs[nb][w * 1024 + 512]);
      asm volatile("s_waitcnt vmcnt(4)" ::: "memory");
    } else {
      asm volatile("s_waitcnt vmcnt(0)" ::: "memory");
    }
    __builtin_amdgcn_s_barrier();
    s16x8 af[4], bf[4];
#pragma unroll
    for (int a = 0; a < 4; a++) af[a] = *(const s16x8*)&As[cb][(wm * 64 + a * 16 + l15) * 32 + l4 * 8];
#pragma unroll
    for (int bb = 0; bb < 4; bb++) bf[bb] = *(const s16x8*)&Bs[cb][(wn * 64 + bb * 16 + l15) * 32 + l4 * 8];
#pragma unroll
    for (int a = 0; a < 4; a++)
#pragma unroll
      for (int bb = 0; bb < 4; bb++)
        acc[a][bb] = __builtin_amdgcn_mfma_f32_16x16x32_bf16(af[a], bf[bb], acc[a][bb], 0, 0, 0);
    asm volatile("s_waitcnt lgkmcnt(0)" ::: "memory");
    __builtin_amdgcn_s_barrier();
  }

#pragma unroll
  for (int bb = 0; bb < 4; bb++) {
    int col = n0 + wn * 64 + bb * 16 + l15;
    float bv = bias[col];
#pragma unroll
    for (int a = 0; a < 4; a++) {
      int row0 = m0 + wm * 64 + a * 16 + l4 * 4;
#pragma unroll
      for (int r = 0; r < 4; r++)
        out[(size_t)(row0 + r) * CC + col] = acc[a][bb][r] + bv;
    }
  }
}

// ---------------------------------------------------------------------------
// ROUND-8: attn split into two kernels (fission for occupancy).
// The fused kernel is reg-capped at 128 unified (2 blocks/CU, 45% occ) by
// pass-2 state it carries through pass 1. Pass 1 alone fits 85 regs ->
// __launch_bounds__(512,6) -> 3 blocks/CU; m-split x2 (grid 8x64x2) supplies
// enough blocks to fill. Partial l goes to workspace (deterministic, no
// atomics); pass 2 sums 2 partials -> log2 -> ll2, then runs the proven
// round-4/6 pass-2 verbatim. Inter-kernel stream order = the only new sync.
// ---------------------------------------------------------------------------

// ---- pass 1: sum-exp partials over half the m-range ----
#define P1_SB   20544             // 512 rows * pitch20 u16 * 2B + 64B tail
#define P1_LP   (P1_SB)           // lpart floats at byte offset
__global__ __launch_bounds__(512, 6) void attn_pass1(
    const u16* __restrict__ qg, const u16* __restrict__ kg,
    const float* __restrict__ wlg, const float* __restrict__ blg,
    float* __restrict__ lout) {
  __shared__ __align__(16) char smem[P1_SB + 8192];
  u16* Sb = (u16*)smem;                   // pitch 20
  float* lpart = (float*)(smem + P1_LP);

  const int b = blockIdx.x, i0 = blockIdx.y * 16, s = blockIdx.z;
  const int tid = threadIdx.x;
  const int w = tid >> 6, lane = tid & 63, l15 = lane & 15, l4 = lane >> 4;
  const float RLN2 = 1.44269504088896340736f;

  for (int j = tid; j < P1_SB / 4; j += 512) ((u32*)smem)[j] = 0;
  __syncthreads();

  s16x8 wlS;
#pragma unroll
  for (int j = 0; j < 8; j++) {
    int k = l4 * 8 + j;
    wlS[j] = (short)((k < 12 && l15 < 12) ? f2bf(wlg[k * 12 + l15] * RLN2) : 0);
  }
  float blv[4];
#pragma unroll
  for (int r = 0; r < 4; r++) {
    int g = l4 * 4 + r;
    blv[r] = (g < 12) ? blg[g] * RLN2 : 0.f;
  }

  int jh[3], jmb[3];
  s16x8 qf[3][2];
#pragma unroll
  for (int jt = 0; jt < 3; jt++) {
    int j = w * 3 + jt;
    jh[jt] = j % 12; jmb[jt] = j / 12;
    const u16* qp = qg + (((size_t)((b * HH + jh[jt]) * NN + i0 + l15)) << 6) + l4 * 8;
    qf[jt][0] = *(const s16x8*)qp;
    qf[jt][1] = *(const s16x8*)(qp + 32);
  }

  float la[4] = {0.f, 0.f, 0.f, 0.f};
  for (int mt = 0; mt < 16; mt++) {
    const int m0 = s * 512 + mt * 32;
#pragma unroll
    for (int jt = 0; jt < 3; jt++) {
      const u16* kp = kg + (((size_t)((b * HH + jh[jt]) * NN + m0 + jmb[jt] * 16 + l15)) << 6) + l4 * 8;
      f32x4 ca = (f32x4){0.f, 0.f, 0.f, 0.f};
      f32x4 cb = (f32x4){0.f, 0.f, 0.f, 0.f};
      ca = __builtin_amdgcn_mfma_f32_16x16x32_bf16(*(const s16x8*)kp, qf[jt][0], ca, 0, 0, 0);
      cb = __builtin_amdgcn_mfma_f32_16x16x32_bf16(*(const s16x8*)(kp + 32), qf[jt][1], cb, 0, 0, 0);
      f32x4 c = ca + cb;
      int cbse = (jmb[jt] * 16 + l4 * 4) * 16 + l15;
#pragma unroll
      for (int r = 0; r < 4; r++)
        Sb[(size_t)(cbse + r * 16) * 20 + jh[jt]] = f2bf(c[r]);
    }
    __syncthreads();
#pragma unroll
    for (int tt = 0; tt < 4; tt++) {
      int t = w * 4 + tt;
      s16x8 bS = lds_read8(Sb + (size_t)(t * 16 + l15) * 20 + l4 * 8);
      f32x4 T = (f32x4){blv[0], blv[1], blv[2], blv[3]};
      T = __builtin_amdgcn_mfma_f32_16x16x32_bf16(wlS, bS, T, 0, 0, 0);
#pragma unroll
      for (int r = 0; r < 4; r++) la[r] += hw_exp2(T[r]);
    }
    __syncthreads();
  }

#pragma unroll
  for (int r = 0; r < 4; r++) lpart[w * 256 + (l4 * 4 + r) * 16 + l15] = la[r];
  __syncthreads();
  if (tid < 256) {
    float sum = 0.f;
#pragma unroll
    for (int w2 = 0; w2 < 8; w2++) sum += lpart[w2 * 256 + tid];
    lout[(((size_t)(b * 64 + blockIdx.y) * 2 + s) << 8) + tid] = sum;
  }
}

// ---- pass 2: full (hi/lo S, in-reg P, PV); reads l partials ----
#define SB_BYTES 28736            // 512*28*2 + 64 tail, zero-inited
#define UT_OFF   SB_BYTES
#define UT_ELE   6912             // 192*36 u16 per buffer
#define LL2_OFF  (SB_BYTES + 27648)
#define SM_TOTAL (LL2_OFF + 1088)

__global__ __launch_bounds__(512, 4) void attn_pass2(
    const u16* __restrict__ qg, const u16* __restrict__ kg, const u16* __restrict__ vtg,
    const float* __restrict__ wlg, const float* __restrict__ blg,
    const float* __restrict__ wwg, const float* __restrict__ bwg,
    const float* __restrict__ lin, u16* __restrict__ aout) {
  __shared__ __align__(16) char smem[SM_TOTAL];
  u16* Sb = (u16*)smem;
  u16* Ut0 = (u16*)(smem + UT_OFF);
  float* ll2 = (float*)(smem + LL2_OFF);    // [16][17]

  const int b = blockIdx.x, i0 = blockIdx.y * 16;
  const int tid = threadIdx.x;
  const int w = tid >> 6, lane = tid & 63, l15 = lane & 15, l4 = lane >> 4;
  const float RLN2 = 1.44269504088896340736f;

  // zero Sb region once: MFMA pads must never be NaN bit patterns
  for (int j = tid; j < SB_BYTES / 4; j += 512) ((u32*)smem)[j] = 0;

  // ll2 from pass-1 partials (l = lp0 + lp1)
  if (tid < 256) {
    size_t base = ((size_t)(b * 64 + blockIdx.y) * 2) << 8;
    float l0 = lin[base + tid];
    float l1 = lin[base + 256 + tid];
    ll2[(tid >> 4) * 17 + (tid & 15)] = hw_log2(l0 + l1);
  }

  // ---- weight A-fragments: lane holds A[row=g=l15][k=l4*8+j] ----
  s16x8 wlA1, wlA2, wwA1, wwA2;
#pragma unroll
  for (int j = 0; j < 8; j++) {
    int k = l4 * 8 + j;
    int h = k >> 1, pt = k & 1;
    float v2 = (h < 12 && l15 < 12) ? wlg[h * 12 + l15] * RLN2 : 0.f;
    u16 h2 = f2bf(v2); u16 lo2 = f2bf(v2 - bf2f(h2));
    wlA1[j] = (short)h2; wlA2[j] = (short)(pt ? 0 : lo2);
    float v3 = (h < 12 && l15 < 12) ? wwg[h * 12 + l15] : 0.f;
    u16 h3 = f2bf(v3); u16 lo3 = f2bf(v3 - bf2f(h3));
    wwA1[j] = (short)h3; wwA2[j] = (short)(pt ? 0 : lo3);
  }
  int gr[4]; float blv[4], bwv[4];
#pragma unroll
  for (int r = 0; r < 4; r++) {
    gr[r] = l4 * 4 + r;
    blv[r] = (gr[r] < 12) ? blg[gr[r]] * RLN2 : 0.f;
    bwv[r] = (gr[r] < 12) ? bwg[gr[r]] : 0.f;
  }

  // ---- QK jobs (12h x 2mb over 8 waves) + Q B-frags ----
  int jh[3], jmb[3];
  s16x8 qf[3][2];
#pragma unroll
  for (int jt = 0; jt < 3; jt++) {
    int j = w * 3 + jt;
    jh[jt] = j % 12; jmb[jt] = j / 12;
    const u16* qp = qg + (((size_t)((b * HH + jh[jt]) * NN + i0 + l15)) << 6) + l4 * 8;
    qf[jt][0] = *(const s16x8*)qp;
    qf[jt][1] = *(const s16x8*)(qp + 32);
  }

  __syncthreads();  // zero + ll2 visible
  float Tinit[4];
#pragma unroll
  for (int r = 0; r < 4; r++) Tinit[r] = blv[r] - ll2[gr[r] * 17 + l15];

  const int db = w >> 1, pvh = (w & 1) * 6;
  f32x4 O[6];
#pragma unroll
  for (int jp = 0; jp < 6; jp++) O[jp] = (f32x4){0.f, 0.f, 0.f, 0.f};

  for (int mt = 0; mt < 32; mt++) {
    const int m0 = mt * 32;
    u16* Utb = Ut0 + (mt & 1) * UT_ELE;
#pragma unroll
    for (int jt = 0; jt < 3; jt++) {
      const u16* kp = kg + (((size_t)((b * HH + jh[jt]) * NN + m0 + jmb[jt] * 16 + l15)) << 6) + l4 * 8;
      f32x4 ca = (f32x4){0.f, 0.f, 0.f, 0.f};
      f32x4 cb = (f32x4){0.f, 0.f, 0.f, 0.f};
      ca = __builtin_amdgcn_mfma_f32_16x16x32_bf16(*(const s16x8*)kp, qf[jt][0], ca, 0, 0, 0);
      cb = __builtin_amdgcn_mfma_f32_16x16x32_bf16(*(const s16x8*)(kp + 32), qf[jt][1], cb, 0, 0, 0);
      f32x4 c = ca + cb;
      int cbse = (jmb[jt] * 16 + l4 * 4) * 16 + l15;
#pragma unroll
      for (int r = 0; r < 4; r++)
        *(u32*)(Sb + (size_t)(cbse + r * 16) * 28 + 2 * jh[jt]) = packhl(c[r]);
    }
    __syncthreads();
#pragma unroll
    for (int tt = 0; tt < 4; tt++) {
      int t = w * 4 + tt;
      s16x8 bS = lds_read8(Sb + (size_t)(t * 16 + l15) * 28 + l4 * 8);
      f32x4 Ta = (f32x4){Tinit[0], Tinit[1], Tinit[2], Tinit[3]};
      f32x4 Tb = (f32x4){0.f, 0.f, 0.f, 0.f};
      Ta = __builtin_amdgcn_mfma_f32_16x16x32_bf16(wlA1, bS, Ta, 0, 0, 0);
      Tb = __builtin_amdgcn_mfma_f32_16x16x32_bf16(wlA2, bS, Tb, 0, 0, 0);
      f32x4 T = Ta + Tb;
      u32x4 pk;
#pragma unroll
      for (int r = 0; r < 4; r++) pk[r] = packhl(hw_exp2(T[r]));  // normalized via Tinit
      s16x8 bP = __builtin_bit_cast(s16x8, pk);  // == ww-mix B-frag in-lane
      f32x4 Ua = (f32x4){bwv[0], bwv[1], bwv[2], bwv[3]};
      f32x4 Ub = (f32x4){0.f, 0.f, 0.f, 0.f};
      Ua = __builtin_amdgcn_mfma_f32_16x16x32_bf16(wwA1, bP, Ua, 0, 0, 0);
      Ub = __builtin_amdgcn_mfma_f32_16x16x32_bf16(wwA2, bP, Ub, 0, 0, 0);
      f32x4 U = Ua + Ub;
#pragma unroll
      for (int r = 0; r < 4; r++)
        if (gr[r] < 12) Utb[(size_t)(gr[r] * 16 + l15) * 36 + t] = f2bf(U[r]);
    }
    __syncthreads();
#pragma unroll
    for (int jp = 0; jp < 6; jp++) {
      const int h = pvh + jp;
      s16x8 aV = *(const s16x8*)(vtg + (((size_t)((b * HH + h) * DD + db * 16 + l15)) << 10) + m0 + l4 * 8);
      s16x8 bU = lds_read8(Utb + (size_t)(h * 16 + l15) * 36 + l4 * 8);
      O[jp] = __builtin_amdgcn_mfma_f32_16x16x32_bf16(aV, bU, O[jp], 0, 0, 0);
    }
  }

  // epilogue: O^T frag rows=d, col=i -> ao[b][n][h*64+d]
#pragma unroll
  for (int jp = 0; jp < 6; jp++) {
    const int h = pvh + jp;
    const int d0 = db * 16 + l4 * 4;
    s16x4 pk4;
#pragma unroll
    for (int r = 0; r < 4; r++) pk4[r] = (short)f2bf(O[jp][r]);
    *(s16x4*)(aout + ((size_t)(b * NN) + i0 + l15) * CC + h * DD + d0) = pk4;
  }
}

extern "C" void kernel_launch(void* const* d_in, const int* in_sizes, int n_in,
                              void* d_out, int out_size, void* d_ws, size_t ws_size,
                              hipStream_t stream) {
  const float* x      = (const float*)d_in[0];
  const float* w_qkv  = (const float*)d_in[1];
  const float* b_qkv  = (const float*)d_in[2];
  const float* w_l    = (const float*)d_in[3];
  const float* b_l    = (const float*)d_in[4];
  const float* w_w    = (const float*)d_in[5];
  const float* b_w    = (const float*)d_in[6];
  const float* w_proj = (const float*)d_in[7];
  const float* b_proj = (const float*)d_in[8];

  const size_t per = (size_t)BB * HH * NN * DD;  // 6,291,456
  u16* xb  = (u16*)d_ws;
  u16* wqt = xb + per;
  u16* wpt = wqt + (size_t)3 * CC * CC;
  u16* q   = wpt + (size_t)CC * CC;
  u16* k   = q + per;
  u16* vt  = k + per;
  u16* ao  = vt + per;
  float* lw = (float*)(ao + per);  // 8*64*2*256 floats = 1 MB partial-l buffer

  convx_kernel<<<3072, 256, 0, stream>>>(x, xb);
  transpose_kernel<<<dim3(3 * CC / 32, CC / 32), 256, 0, stream>>>(w_qkv, wqt, CC, 3 * CC);
  transpose_kernel<<<dim3(CC / 32, CC / 32), 256, 0, stream>>>(w_proj, wpt, CC, CC);
  qkv_gemm<<<dim3(64, 18), 256, 0, stream>>>(xb, wqt, b_qkv, q, k, vt);
  attn_pass1<<<dim3(BB, NN / 16, 2), 512, 0, stream>>>(q, k, w_l, b_l, lw);
  attn_pass2<<<dim3(BB, NN / 16), 512, 0, stream>>>(q, k, vt, w_l, b_l, w_w, b_w, lw, ao);
  proj_gemm<<<dim3(64, 6), 256, 0, stream>>>(ao, wpt, b_proj, (float*)d_out);
}

// Round 9
// 442.247 us; speedup vs baseline: 1.0967x; 1.0967x over previous
//
#include <hip/hip_runtime.h>

#define BB 8
#define NN 1024
#define CC 768
#define HH 12
#define DD 64

typedef unsigned short u16;
typedef unsigned int u32;
typedef __attribute__((ext_vector_type(8))) short s16x8;
typedef __attribute__((ext_vector_type(4))) short s16x4;
typedef __attribute__((ext_vector_type(4))) float f32x4;
typedef __attribute__((ext_vector_type(2))) u32 u32x2;
typedef __attribute__((ext_vector_type(4))) u32 u32x4;

__device__ __forceinline__ float bf2f(u16 u) {
  u32 x = ((u32)u) << 16;
  return __builtin_bit_cast(float, x);
}
__device__ __forceinline__ u16 f2bf(float f) {
  u32 x = __builtin_bit_cast(u32, f);
  x += 0x7fffu + ((x >> 16) & 1u);
  return (u16)(x >> 16);
}
// hardware exp2 / log2 (v_exp_f32 / v_log_f32)
__device__ __forceinline__ float hw_exp2(float x) { return __builtin_amdgcn_exp2f(x); }
__device__ __forceinline__ float hw_log2(float x) { return __builtin_amdgcn_logf(x); }
// 16B LDS read as 2x8B (rows are 8B- but not 16B-aligned at conflict-free pitches)
__device__ __forceinline__ s16x8 lds_read8(const u16* p) {
  u32x2 a = *(const u32x2*)p;
  u32x2 b = *(const u32x2*)(p + 4);
  u32x4 m = {a.x, a.y, b.x, b.y};
  return __builtin_bit_cast(s16x8, m);
}
// pack f32 v into u32: low16 = bf16-trunc(v), high16 = bf16-trunc(v - hi).
// 4 VALU vs ~8 for RNE f2bf pair; err <= 2^-16|v|. Verified round-2/4.
__device__ __forceinline__ u32 packhl(float v) {
  u32 xv = __builtin_bit_cast(u32, v);
  float lo = v - __builtin_bit_cast(float, xv & 0xFFFF0000u);
  return (xv >> 16) | (__builtin_bit_cast(u32, lo) & 0xFFFF0000u);
}
// async global->LDS 16B/lane. LDS dest is wave-uniform base + lane*16.
__device__ __forceinline__ void gload_lds16(const u16* g, u16* l) {
  __builtin_amdgcn_global_load_lds(
      (const __attribute__((address_space(1))) u32*)g,
      (__attribute__((address_space(3))) u32*)l, 16, 0, 0);
}

// ---------------------------------------------------------------------------
// ROUND-9: fused prep kernel — convx (3072 blocks) + w_qkv transpose (1728)
// + w_proj transpose (576) in one dispatch, selected by block-id range.
// Branches are block-uniform; all jobs are 256-thread memory-bound.
// Saves 2 launch gaps and packs the small transpose tails alongside convx.
// ---------------------------------------------------------------------------
__device__ __forceinline__ void transpose_block(const float* __restrict__ in,
                                                u16* __restrict__ out,
                                                int R, int C, int bx, int by,
                                                float (*t)[33]) {
  const int cl = threadIdx.x & 31, rq = threadIdx.x >> 5;
#pragma unroll
  for (int rr = 0; rr < 4; rr++) {
    int rl = rq * 4 + rr;
    t[rl][cl] = in[(size_t)(by * 32 + rl) * C + bx * 32 + cl];
  }
  __syncthreads();
#pragma unroll
  for (int rr = 0; rr < 4; rr++) {
    int oc = rq * 4 + rr;
    out[(size_t)(bx * 32 + oc) * R + by * 32 + cl] = f2bf(t[cl][oc]);
  }
}

__global__ __launch_bounds__(256) void prep_kernel(
    const float* __restrict__ x, u16* __restrict__ xb,
    const float* __restrict__ w_qkv, u16* __restrict__ wqt,
    const float* __restrict__ w_proj, u16* __restrict__ wpt) {
  __shared__ float t[32][33];
  int id = blockIdx.x;
  if (id < 3072) {
    size_t i = ((size_t)id * 256 + threadIdx.x) * 8;
    f32x4 a = *(const f32x4*)(x + i);
    f32x4 b = *(const f32x4*)(x + i + 4);
    s16x8 r;
#pragma unroll
    for (int j = 0; j < 4; j++) { r[j] = (short)f2bf(a[j]); r[4 + j] = (short)f2bf(b[j]); }
    *(s16x8*)(xb + i) = r;
    return;
  }
  id -= 3072;
  if (id < 1728) {
    transpose_block(w_qkv, wqt, CC, 3 * CC, id % 72, id / 72, t);
  } else {
    id -= 1728;
    transpose_block(w_proj, wpt, CC, CC, id % 24, id / 24, t);
  }
}

// ---------------------------------------------------------------------------
// QKV GEMM: 128x128 tile, BK=32, dbuf prefetch w/ counted vmcnt (r7, neutral
// but kept) -> q,k [b][h][n][d] (q x0.125), v^T [b][h][d][n]
// ---------------------------------------------------------------------------
__global__ __launch_bounds__(256) void qkv_gemm(
    const u16* __restrict__ A, const u16* __restrict__ Bt, const float* __restrict__ bias,
    u16* __restrict__ qo, u16* __restrict__ ko, u16* __restrict__ vo) {
  __shared__ __align__(16) u16 As[2][128 * 32];
  __shared__ __align__(16) u16 Bs[2][128 * 32];
  const int tid = threadIdx.x;
  const int w = tid >> 6, lane = tid & 63, l15 = lane & 15, l4 = lane >> 4;
  const int wm = w & 1, wn = w >> 1;
  const int m0 = blockIdx.x * 128, n0 = blockIdx.y * 128;
  const int grow = lane >> 2, gcol = (lane & 3) * 8;  // staging row-in-chunk / u16 col

  const u16* ga0 = A + (size_t)(m0 + w * 32 + grow) * CC + gcol;
  const u16* gb0 = Bt + (size_t)(n0 + w * 32 + grow) * CC + gcol;

  f32x4 acc[4][4];
#pragma unroll
  for (int a = 0; a < 4; a++)
#pragma unroll
    for (int bb = 0; bb < 4; bb++) acc[a][bb] = (f32x4){0.f, 0.f, 0.f, 0.f};

  gload_lds16(ga0, &As[0][w * 1024]);
  gload_lds16(ga0 + (size_t)16 * CC, &As[0][w * 1024 + 512]);
  gload_lds16(gb0, &Bs[0][w * 1024]);
  gload_lds16(gb0 + (size_t)16 * CC, &Bs[0][w * 1024 + 512]);

  for (int t = 0; t < 24; ++t) {
    const int cb = t & 1, nb = cb ^ 1;
    if (t + 1 < 24) {
      const u16* ga = ga0 + (t + 1) * 32;
      const u16* gb = gb0 + (t + 1) * 32;
      gload_lds16(ga, &As[nb][w * 1024]);
      gload_lds16(ga + (size_t)16 * CC, &As[nb][w * 1024 + 512]);
      gload_lds16(gb, &Bs[nb][w * 1024]);
      gload_lds16(gb + (size_t)16 * CC, &Bs[nb][w * 1024 + 512]);
      asm volatile("s_waitcnt vmcnt(4)" ::: "memory");
    } else {
      asm volatile("s_waitcnt vmcnt(0)" ::: "memory");
    }
    __builtin_amdgcn_s_barrier();
    s16x8 af[4], bf[4];
#pragma unroll
    for (int a = 0; a < 4; a++) af[a] = *(const s16x8*)&As[cb][(wm * 64 + a * 16 + l15) * 32 + l4 * 8];
#pragma unroll
    for (int bb = 0; bb < 4; bb++) bf[bb] = *(const s16x8*)&Bs[cb][(wn * 64 + bb * 16 + l15) * 32 + l4 * 8];
#pragma unroll
    for (int a = 0; a < 4; a++)
#pragma unroll
      for (int bb = 0; bb < 4; bb++)
        acc[a][bb] = __builtin_amdgcn_mfma_f32_16x16x32_bf16(af[a], bf[bb], acc[a][bb], 0, 0, 0);
    asm volatile("s_waitcnt lgkmcnt(0)" ::: "memory");
    __builtin_amdgcn_s_barrier();
  }

  const int b = (m0 >> 10);
#pragma unroll
  for (int bb = 0; bb < 4; bb++) {
    int col = n0 + wn * 64 + bb * 16 + l15;
    int s = col / CC;
    int rem = col - s * CC;
    int h = rem >> 6, d = rem & 63;
    float bv = bias[col];
#pragma unroll
    for (int a = 0; a < 4; a++) {
      int row0 = m0 + wm * 64 + a * 16 + l4 * 4;
      int nt0 = row0 & (NN - 1);
      if (s == 2) {
        s16x4 pk;
#pragma unroll
        for (int r = 0; r < 4; r++) pk[r] = (short)f2bf(acc[a][bb][r] + bv);
        *(s16x4*)(vo + (((size_t)((b * HH + h) * DD + d)) << 10) + nt0) = pk;
      } else if (s == 0) {
#pragma unroll
        for (int r = 0; r < 4; r++)
          qo[(((size_t)((b * HH + h) * NN + nt0 + r)) << 6) + d] = f2bf((acc[a][bb][r] + bv) * 0.125f);
      } else {
#pragma unroll
        for (int r = 0; r < 4; r++)
          ko[(((size_t)((b * HH + h) * NN + nt0 + r)) << 6) + d] = f2bf(acc[a][bb][r] + bv);
      }
    }
  }
}

// ---------------------------------------------------------------------------
// Proj GEMM -> fp32 out (same structure)
// ---------------------------------------------------------------------------
__global__ __launch_bounds__(256) void proj_gemm(
    const u16* __restrict__ A, const u16* __restrict__ Bt, const float* __restrict__ bias,
    float* __restrict__ out) {
  __shared__ __align__(16) u16 As[2][128 * 32];
  __shared__ __align__(16) u16 Bs[2][128 * 32];
  const int tid = threadIdx.x;
  const int w = tid >> 6, lane = tid & 63, l15 = lane & 15, l4 = lane >> 4;
  const int wm = w & 1, wn = w >> 1;
  const int m0 = blockIdx.x * 128, n0 = blockIdx.y * 128;
  const int grow = lane >> 2, gcol = (lane & 3) * 8;

  const u16* ga0 = A + (size_t)(m0 + w * 32 + grow) * CC + gcol;
  const u16* gb0 = Bt + (size_t)(n0 + w * 32 + grow) * CC + gcol;

  f32x4 acc[4][4];
#pragma unroll
  for (int a = 0; a < 4; a++)
#pragma unroll
    for (int bb = 0; bb < 4; bb++) acc[a][bb] = (f32x4){0.f, 0.f, 0.f, 0.f};

  gload_lds16(ga0, &As[0][w * 1024]);
  gload_lds16(ga0 + (size_t)16 * CC, &As[0][w * 1024 + 512]);
  gload_lds16(gb0, &Bs[0][w * 1024]);
  gload_lds16(gb0 + (size_t)16 * CC, &Bs[0][w * 1024 + 512]);

  for (int t = 0; t < 24; ++t) {
    const int cb = t & 1, nb = cb ^ 1;
    if (t + 1 < 24) {
      const u16* ga = ga0 + (t + 1) * 32;
      const u16* gb = gb0 + (t + 1) * 32;
      gload_lds16(ga, &As[nb][w * 1024]);
      gload_lds16(ga + (size_t)16 * CC, &As[nb][w * 1024 + 512]);
      gload_lds16(gb, &Bs[nb][w * 1024]);
      gload_lds16(gb + (size_t)16 * CC, &Bs[nb][w * 1024 + 512]);
      asm volatile("s_waitcnt vmcnt(4)" ::: "memory");
    } else {
      asm volatile("s_waitcnt vmcnt(0)" ::: "memory");
    }
    __builtin_amdgcn_s_barrier();
    s16x8 af[4], bf[4];
#pragma unroll
    for (int a = 0; a < 4; a++) af[a] = *(const s16x8*)&As[cb][(wm * 64 + a * 16 + l15) * 32 + l4 * 8];
#pragma unroll
    for (int bb = 0; bb < 4; bb++) bf[bb] = *(const s16x8*)&Bs[cb][(wn * 64 + bb * 16 + l15) * 32 + l4 * 8];
#pragma unroll
    for (int a = 0; a < 4; a++)
#pragma unroll
      for (int bb = 0; bb < 4; bb++)
        acc[a][bb] = __builtin_amdgcn_mfma_f32_16x16x32_bf16(af[a], bf[bb], acc[a][bb], 0, 0, 0);
    asm volatile("s_waitcnt lgkmcnt(0)" ::: "memory");
    __builtin_amdgcn_s_barrier();
  }

#pragma unroll
  for (int bb = 0; bb < 4; bb++) {
    int col = n0 + wn * 64 + bb * 16 + l15;
    float bv = bias[col];
#pragma unroll
    for (int a = 0; a < 4; a++) {
      int row0 = m0 + wm * 64 + a * 16 + l4 * 4;
#pragma unroll
      for (int r = 0; r < 4; r++)
        out[(size_t)(row0 + r) * CC + col] = acc[a][bb][r] + bv;
    }
  }
}

// ---------------------------------------------------------------------------
// Talking-heads attention — fused, round-7 state verbatim (measured 299us).
// Structural-change ledger: r1 PV-pipeline (+48 regs) -> spill, 28x HBM;
// r2 p1-dbuf+setprio -> +31us; r5 KVBLK64+PV-group -> +28us; r6 chain-split
// -> null; r8 fission -> +39us. VGPR 64 + AGPR 64 = exactly the 128-unified
// cap of (512,4): zero register headroom is the binding constraint.
// pass1: QK -> Sb (bf16 single, pitch 20), T=wl'.S+bl' (1 MFMA), l += exp2(T)
// between: ll2 = log2(l);  Tinit = bl' - ll2   (folds 1/l into C-init)
// pass2: QK -> Sb hi/lo (pitch 28, packhl), T via 2 MFMA, P=exp2(T) packed
//        hi/lo in regs == ww B-frag, U via 2 MFMA + bw -> Ut (pitch 36, dbuf),
//        O^T += mfma(V^T global, Ut)
// Pitches 20/28/36 u16 = 10/14/18-bank strides (gcd 2 with 32 -> free).
// ---------------------------------------------------------------------------
#define SB_BYTES 28736            // 512*28*2 + 64 tail, zero-inited
#define UT_OFF   SB_BYTES
#define UT_ELE   6912             // 192*36 u16 per buffer
#define LL2_OFF  (SB_BYTES + 27648)
#define SM_TOTAL (LL2_OFF + 1088)

__global__ __launch_bounds__(512, 4) void attn_kernel(
    const u16* __restrict__ qg, const u16* __restrict__ kg, const u16* __restrict__ vtg,
    const float* __restrict__ wlg, const float* __restrict__ blg,
    const float* __restrict__ wwg, const float* __restrict__ bwg,
    u16* __restrict__ aout) {
  __shared__ __align__(16) char smem[SM_TOTAL];
  u16* Sb = (u16*)smem;
  u16* Ut0 = (u16*)(smem + UT_OFF);
  float* lpart = (float*)(smem + UT_OFF);   // 8KB, consumed before Ut use
  float* ll2 = (float*)(smem + LL2_OFF);    // [16][17]

  const int b = blockIdx.x, i0 = blockIdx.y * 16;
  const int tid = threadIdx.x;
  const int w = tid >> 6, lane = tid & 63, l15 = lane & 15, l4 = lane >> 4;
  const float RLN2 = 1.44269504088896340736f;

  // zero Sb region once: MFMA pads must never be NaN bit patterns
  for (int j = tid; j < SB_BYTES / 4; j += 512) ((u32*)smem)[j] = 0;
  __syncthreads();  // zero visible before any S writes

  // ---- weight A-fragments: lane holds A[row=g=l15][k=l4*8+j] ----
  s16x8 wlS, wlA1, wlA2, wwA1, wwA2;
#pragma unroll
  for (int j = 0; j < 8; j++) {
    int k = l4 * 8 + j;
    float v1 = (k < 12 && l15 < 12) ? wlg[k * 12 + l15] * RLN2 : 0.f;
    wlS[j] = (short)f2bf(v1);
    int h = k >> 1, pt = k & 1;
    float v2 = (h < 12 && l15 < 12) ? wlg[h * 12 + l15] * RLN2 : 0.f;
    u16 h2 = f2bf(v2); u16 lo2 = f2bf(v2 - bf2f(h2));
    wlA1[j] = (short)h2; wlA2[j] = (short)(pt ? 0 : lo2);
    float v3 = (h < 12 && l15 < 12) ? wwg[h * 12 + l15] : 0.f;
    u16 h3 = f2bf(v3); u16 lo3 = f2bf(v3 - bf2f(h3));
    wwA1[j] = (short)h3; wwA2[j] = (short)(pt ? 0 : lo3);
  }
  int gr[4]; float blv[4], bwv[4];
#pragma unroll
  for (int r = 0; r < 4; r++) {
    gr[r] = l4 * 4 + r;
    blv[r] = (gr[r] < 12) ? blg[gr[r]] * RLN2 : 0.f;
    bwv[r] = (gr[r] < 12) ? bwg[gr[r]] : 0.f;
  }

  // ---- QK jobs (12h x 2mb over 8 waves) + Q B-frags ----
  int jh[3], jmb[3];
  s16x8 qf[3][2];
#pragma unroll
  for (int jt = 0; jt < 3; jt++) {
    int j = w * 3 + jt;
    jh[jt] = j % 12; jmb[jt] = j / 12;
    const u16* qp = qg + (((size_t)((b * HH + jh[jt]) * NN + i0 + l15)) << 6) + l4 * 8;
    qf[jt][0] = *(const s16x8*)qp;
    qf[jt][1] = *(const s16x8*)(qp + 32);
  }

  // ================= pass 1: sum-exp (single-bf16 S) =================
  float la[4] = {0.f, 0.f, 0.f, 0.f};
  for (int mt = 0; mt < 32; mt++) {
    const int m0 = mt * 32;
#pragma unroll
    for (int jt = 0; jt < 3; jt++) {
      const u16* kp = kg + (((size_t)((b * HH + jh[jt]) * NN + m0 + jmb[jt] * 16 + l15)) << 6) + l4 * 8;
      f32x4 ca = (f32x4){0.f, 0.f, 0.f, 0.f};
      f32x4 cb = (f32x4){0.f, 0.f, 0.f, 0.f};
      ca = __builtin_amdgcn_mfma_f32_16x16x32_bf16(*(const s16x8*)kp, qf[jt][0], ca, 0, 0, 0);
      cb = __builtin_amdgcn_mfma_f32_16x16x32_bf16(*(const s16x8*)(kp + 32), qf[jt][1], cb, 0, 0, 0);
      f32x4 c = ca + cb;
      int cbse = (jmb[jt] * 16 + l4 * 4) * 16 + l15;
#pragma unroll
      for (int r = 0; r < 4; r++)
        Sb[(size_t)(cbse + r * 16) * 20 + jh[jt]] = f2bf(c[r]);
    }
    __syncthreads();
#pragma unroll
    for (int tt = 0; tt < 4; tt++) {
      int t = w * 4 + tt;
      s16x8 bS = lds_read8(Sb + (size_t)(t * 16 + l15) * 20 + l4 * 8);
      f32x4 T = (f32x4){blv[0], blv[1], blv[2], blv[3]};
      T = __builtin_amdgcn_mfma_f32_16x16x32_bf16(wlS, bS, T, 0, 0, 0);
#pragma unroll
      for (int r = 0; r < 4; r++) la[r] += hw_exp2(T[r]);
    }
    __syncthreads();
  }

  // ---- reduce l across waves; Tinit = bl' - log2(l) ----
#pragma unroll
  for (int r = 0; r < 4; r++) lpart[w * 256 + gr[r] * 16 + l15] = la[r];
  __syncthreads();
  if (tid < 256) {
    float s = 0.f;
#pragma unroll
    for (int w2 = 0; w2 < 8; w2++) s += lpart[w2 * 256 + tid];
    ll2[(tid >> 4) * 17 + (tid & 15)] = hw_log2(s);
  }
  __syncthreads();
  float Tinit[4];
#pragma unroll
  for (int r = 0; r < 4; r++) Tinit[r] = blv[r] - ll2[gr[r] * 17 + l15];

  // ================= pass 2: full (hi/lo S, in-reg P, PV) =================
  const int db = w >> 1, pvh = (w & 1) * 6;
  f32x4 O[6];
#pragma unroll
  for (int jp = 0; jp < 6; jp++) O[jp] = (f32x4){0.f, 0.f, 0.f, 0.f};

  for (int mt = 0; mt < 32; mt++) {
    const int m0 = mt * 32;
    u16* Utb = Ut0 + (mt & 1) * UT_ELE;
#pragma unroll
    for (int jt = 0; jt < 3; jt++) {
      const u16* kp = kg + (((size_t)((b * HH + jh[jt]) * NN + m0 + jmb[jt] * 16 + l15)) << 6) + l4 * 8;
      f32x4 ca = (f32x4){0.f, 0.f, 0.f, 0.f};
      f32x4 cb = (f32x4){0.f, 0.f, 0.f, 0.f};
      ca = __builtin_amdgcn_mfma_f32_16x16x32_bf16(*(const s16x8*)kp, qf[jt][0], ca, 0, 0, 0);
      cb = __builtin_amdgcn_mfma_f32_16x16x32_bf16(*(const s16x8*)(kp + 32), qf[jt][1], cb, 0, 0, 0);
      f32x4 c = ca + cb;
      int cbse = (jmb[jt] * 16 + l4 * 4) * 16 + l15;
#pragma unroll
      for (int r = 0; r < 4; r++)
        *(u32*)(Sb + (size_t)(cbse + r * 16) * 28 + 2 * jh[jt]) = packhl(c[r]);
    }
    __syncthreads();
#pragma unroll
    for (int tt = 0; tt < 4; tt++) {
      int t = w * 4 + tt;
      s16x8 bS = lds_read8(Sb + (size_t)(t * 16 + l15) * 28 + l4 * 8);
      f32x4 Ta = (f32x4){Tinit[0], Tinit[1], Tinit[2], Tinit[3]};
      f32x4 Tb = (f32x4){0.f, 0.f, 0.f, 0.f};
      Ta = __builtin_amdgcn_mfma_f32_16x16x32_bf16(wlA1, bS, Ta, 0, 0, 0);
      Tb = __builtin_amdgcn_mfma_f32_16x16x32_bf16(wlA2, bS, Tb, 0, 0, 0);
      f32x4 T = Ta + Tb;
      u32x4 pk;
#pragma unroll
      for (int r = 0; r < 4; r++) pk[r] = packhl(hw_exp2(T[r]));  // normalized via Tinit
      s16x8 bP = __builtin_bit_cast(s16x8, pk);  // == ww-mix B-frag in-lane
      f32x4 Ua = (f32x4){bwv[0], bwv[1], bwv[2], bwv[3]};
      f32x4 Ub = (f32x4){0.f, 0.f, 0.f, 0.f};
      Ua = __builtin_amdgcn_mfma_f32_16x16x32_bf16(wwA1, bP, Ua, 0, 0, 0);
      Ub = __builtin_amdgcn_mfma_f32_16x16x32_bf16(wwA2, bP, Ub, 0, 0, 0);
      f32x4 U = Ua + Ub;
#pragma unroll
      for (int r = 0; r < 4; r++)
        if (gr[r] < 12) Utb[(size_t)(gr[r] * 16 + l15) * 36 + t] = f2bf(U[r]);
    }
    __syncthreads();
#pragma unroll
    for (int jp = 0; jp < 6; jp++) {
      const int h = pvh + jp;
      s16x8 aV = *(const s16x8*)(vtg + (((size_t)((b * HH + h) * DD + db * 16 + l15)) << 10) + m0 + l4 * 8);
      s16x8 bU = lds_read8(Utb + (size_t)(h * 16 + l15) * 36 + l4 * 8);
      O[jp] = __builtin_amdgcn_mfma_f32_16x16x32_bf16(aV, bU, O[jp], 0, 0, 0);
    }
  }

  // epilogue: O^T frag rows=d, col=i -> ao[b][n][h*64+d]
#pragma unroll
  for (int jp = 0; jp < 6; jp++) {
    const int h = pvh + jp;
    const int d0 = db * 16 + l4 * 4;
    s16x4 pk4;
#pragma unroll
    for (int r = 0; r < 4; r++) pk4[r] = (short)f2bf(O[jp][r]);
    *(s16x4*)(aout + ((size_t)(b * NN) + i0 + l15) * CC + h * DD + d0) = pk4;
  }
}

extern "C" void kernel_launch(void* const* d_in, const int* in_sizes, int n_in,
                              void* d_out, int out_size, void* d_ws, size_t ws_size,
                              hipStream_t stream) {
  const float* x      = (const float*)d_in[0];
  const float* w_qkv  = (const float*)d_in[1];
  const float* b_qkv  = (const float*)d_in[2];
  const float* w_l    = (const float*)d_in[3];
  const float* b_l    = (const float*)d_in[4];
  const float* w_w    = (const float*)d_in[5];
  const float* b_w    = (const float*)d_in[6];
  const float* w_proj = (const float*)d_in[7];
  const float* b_proj = (const float*)d_in[8];

  const size_t per = (size_t)BB * HH * NN * DD;  // 6,291,456
  u16* xb  = (u16*)d_ws;
  u16* wqt = xb + per;
  u16* wpt = wqt + (size_t)3 * CC * CC;
  u16* q   = wpt + (size_t)CC * CC;
  u16* k   = q + per;
  u16* vt  = k + per;
  u16* ao  = vt + per;

  prep_kernel<<<3072 + 1728 + 576, 256, 0, stream>>>(x, xb, w_qkv, wqt, w_proj, wpt);
  qkv_gemm<<<dim3(64, 18), 256, 0, stream>>>(xb, wqt, b_qkv, q, k, vt);
  attn_kernel<<<dim3(BB, NN / 16), 512, 0, stream>>>(q, k, vt, w_l, b_l, w_w, b_w, ao);
  proj_gemm<<<dim3(64, 6), 256, 0, stream>>>(ao, wpt, b_proj, (float*)d_out);
}